// Round 17
// baseline (187.553 us; speedup 1.0000x reference)
//
#include <hip/hip_runtime.h>
#include <hip/hip_bf16.h>

// Problem constants (from reference)
constexpr int N  = 50000;   // nodes
constexpr int E  = 800000;  // edges
constexpr int D0 = 64;      // IN_DIM
constexpr int D1 = 128;     // HID_DIM

// Sub-binned adjacency: neighbors bucketed by src range (src>>13), so the
// gather can walk phases of ~2MB source working set (fits per-XCD L2).
constexpr int SB   = 7;     // src ranges: 50000/8192 -> sb in 0..6
constexpr int SC   = 16;    // per-sub-bin capacity (Poisson(2.62); P(>16)~3e-9)
constexpr int BSTR = 128;   // bin row stride in ushorts (8 sub-bins padded)

constexpr int NPART = 8;                       // XCD count
constexpr int PSZ   = (N + NPART - 1) / NPART; // 6250 nodes per partition
constexpr int BPP   = 128;                     // blocks per partition

typedef __attribute__((ext_vector_type(8))) short short8;   // 8 bf16 = 4 VGPR
typedef __attribute__((ext_vector_type(4))) float f32x4;

__device__ __forceinline__ unsigned short bf16bits(float f) {
    __hip_bfloat16 hb = __float2bfloat16(f);
    return *reinterpret_cast<unsigned short*>(&hb);
}

// accumulate 8 bf16 (packed in uint4) into 8 f32 accumulators
__device__ __forceinline__ void acc8(float* a, const uint4 r) {
    union { unsigned u; float f; } c;
    c.u = r.x << 16;         a[0] += c.f;
    c.u = r.x & 0xffff0000u; a[1] += c.f;
    c.u = r.y << 16;         a[2] += c.f;
    c.u = r.y & 0xffff0000u; a[3] += c.f;
    c.u = r.z << 16;         a[4] += c.f;
    c.u = r.z & 0xffff0000u; a[5] += c.f;
    c.u = r.w << 16;         a[6] += c.f;
    c.u = r.w & 0xffff0000u; a[7] += c.f;
}

// ---------------------------------------------------------------------------
// Fused prep: zero cnt8, convert x -> bf16, pack weights -> bf16.
// ---------------------------------------------------------------------------
__global__ __launch_bounds__(256)
void k_prep(const float* __restrict__ x, unsigned short* __restrict__ xb,
            const float* __restrict__ W1l, const float* __restrict__ W1r,
            const float* __restrict__ W2l, const float* __restrict__ W2r,
            unsigned short* __restrict__ W1cat, unsigned short* __restrict__ W2cat,
            int* __restrict__ cnt8) {
    int i = blockIdx.x * blockDim.x + threadIdx.x;
    if (i < N * 8 / 4) ((int4*)cnt8)[i] = make_int4(0, 0, 0, 0);
    if (i < 128 * 128) {
        int o = i >> 7, k = i & 127;
        float v = (k < 64) ? W1l[o * 64 + k] : W1r[o * 64 + (k - 64)];
        W1cat[i] = bf16bits(v);
    }
    if (i < 128 * 256) {
        int o = i >> 8, k = i & 255;
        float v = (k < 128) ? W2l[o * 128 + k] : W2r[o * 128 + (k - 128)];
        W2cat[i] = bf16bits(v);
    }
    if (i < N * D0 / 8) {
        const float4 v0 = *(const float4*)&x[(size_t)i * 8];
        const float4 v1 = *(const float4*)&x[(size_t)i * 8 + 4];
        float f[8] = {v0.x, v0.y, v0.z, v0.w, v1.x, v1.y, v1.z, v1.w};
        unsigned short u[8];
        #pragma unroll
        for (int j = 0; j < 8; ++j) u[j] = bf16bits(f[j]);
        *(short8*)&xb[(size_t)i * 8] = *(short8*)u;
    }
}

// ---------------------------------------------------------------------------
// XCD-partitioned binning into src-range sub-bins: blocks with blockIdx%8==p
// handle dst range [p*PSZ,(p+1)*PSZ) exclusively (cnt8 atomics + bin stores
// stay in one XCD's L2). Sub-bin sb = src>>13 orders each node's neighbor
// list by source range for the phased gather. Mapping is a locality
// heuristic only (G16).
// ---------------------------------------------------------------------------
__global__ __launch_bounds__(256)
void k_bin(const int* __restrict__ src, const int* __restrict__ dst,
           int* __restrict__ cnt8, unsigned short* __restrict__ bin) {
    const int p     = blockIdx.x & (NPART - 1);   // partition = XCD guess
    const int local = blockIdx.x >> 3;            // 0..BPP-1
    const int lo = p * PSZ;
    const int hi = min(N, lo + PSZ);

    for (int i = local * 256 + threadIdx.x; i < E / 4; i += BPP * 256) {
        const int e0 = i * 4;
        int4 d = *(const int4*)&dst[e0];
        int4 s = *(const int4*)&src[e0];
        if (d.x >= lo && d.x < hi) {
            int sb = s.x >> 13;
            int pos = atomicAdd(&cnt8[d.x * 8 + sb], 1);
            if (pos < SC) bin[(size_t)d.x * BSTR + sb * SC + pos] = (unsigned short)s.x;
        }
        if (d.y >= lo && d.y < hi) {
            int sb = s.y >> 13;
            int pos = atomicAdd(&cnt8[d.y * 8 + sb], 1);
            if (pos < SC) bin[(size_t)d.y * BSTR + sb * SC + pos] = (unsigned short)s.y;
        }
        if (d.z >= lo && d.z < hi) {
            int sb = s.z >> 13;
            int pos = atomicAdd(&cnt8[d.z * 8 + sb], 1);
            if (pos < SC) bin[(size_t)d.z * BSTR + sb * SC + pos] = (unsigned short)s.z;
        }
        if (d.w >= lo && d.w < hi) {
            int sb = s.w >> 13;
            int pos = atomicAdd(&cnt8[d.w * 8 + sb], 1);
            if (pos < SC) bin[(size_t)d.w * BSTR + sb * SC + pos] = (unsigned short)s.w;
        }
    }
}

// ---------------------------------------------------------------------------
// Fused SAGE layer: PHASED gather-mean (phase A) + MFMA dense (phase B).
// Phase A walks src-range sub-bins in order (sb=0..6) with __syncthreads
// between phases: all blocks are co-resident, so the whole device reads a
// ~2MB source range at a time -> per-XCD working set fits 4MB L2, converting
// the ~50% L2 thrash misses (round 16 counters) into hits. Accumulators for
// NPG=2 nodes live in registers across phases (statically indexed).
// Phase B: mfma_f32_16x16x32_bf16 as before (layouts per m89/m91).
// ---------------------------------------------------------------------------
template<int DIN, int NT, bool RELU, bool OUT_BF16>
__global__ __launch_bounds__(256)
void k_layer(const unsigned short* __restrict__ xin,  // bf16 [N][DIN]
             const int* __restrict__ cnt8,            // [N][8] sub-counts
             const unsigned short* __restrict__ bin,  // [N][BSTR] ushort ids
             const unsigned short* __restrict__ Wcat, // [128][2*DIN] bf16
             const float* __restrict__ bias,
             void* __restrict__ out,
             int n_nodes) {
    constexpr int K  = 2 * DIN;       // 128 or 256
    constexpr int KP = K + 8;         // padded row (bf16 units)
    __shared__ unsigned short A[NT * KP];

    const int tid   = threadIdx.x;
    const int nbase = blockIdx.x * NT;

    // ---- Phase A1: root copy into right half of A ----
    constexpr int CPR = DIN / 8;      // 8-elem chunks per row (root half)
    for (int c = tid; c < NT * CPR; c += 256) {
        int row  = c / CPR;
        int col8 = (c - row * CPR) * 8;
        int n    = nbase + row;
        short8 v = (short8)0;
        if (n < n_nodes) v = *(const short8*)&xin[(size_t)n * DIN + col8];
        *(short8*)&A[row * KP + DIN + col8] = v;
    }

    // ---- Phase A2: phased gather-mean into left half of A ----
    {
        constexpr int GRPSZ = DIN / 8;      // 8 (D0) or 16 (D1)
        constexpr int NGRP  = 256 / GRPSZ;  // 32 or 16 groups per block
        constexpr int NPG   = NT / NGRP;    // 2 nodes per group (both layers)
        const int sub      = tid & (GRPSZ - 1);
        const int gloc     = tid / GRPSZ;
        const int lane     = tid & 63;
        const int lanebase = (lane / GRPSZ) * GRPSZ;

        float a[NPG][8];
        int   dg[NPG];
        #pragma unroll
        for (int i = 0; i < NPG; ++i) {
            dg[i] = 0;
            #pragma unroll
            for (int q = 0; q < 8; ++q) a[i][q] = 0.0f;
        }

        for (int sb = 0; sb < SB; ++sb) {
            #pragma unroll
            for (int i = 0; i < NPG; ++i) {
                const int row = gloc * NPG + i;
                const int n   = nbase + row;
                if (n < n_nodes) {
                    const int raw = cnt8[n * 8 + sb];
                    dg[i] += raw;
                    const int c = min(raw, SC);
                    const size_t base = (size_t)n * BSTR + sb * SC;
                    for (int b = 0; b < c; b += GRPSZ) {
                        int nb = (b + sub < c) ? (int)bin[base + b + sub] : 0;
                        const int cc = min(GRPSZ, c - b);
                        int j = 0;
                        for (; j + 4 <= cc; j += 4) {
                            int s0 = __shfl(nb, lanebase + j + 0);
                            int s1 = __shfl(nb, lanebase + j + 1);
                            int s2 = __shfl(nb, lanebase + j + 2);
                            int s3 = __shfl(nb, lanebase + j + 3);
                            uint4 r0 = *(const uint4*)&xin[(size_t)s0 * DIN + sub * 8];
                            uint4 r1 = *(const uint4*)&xin[(size_t)s1 * DIN + sub * 8];
                            uint4 r2 = *(const uint4*)&xin[(size_t)s2 * DIN + sub * 8];
                            uint4 r3 = *(const uint4*)&xin[(size_t)s3 * DIN + sub * 8];
                            acc8(a[i], r0); acc8(a[i], r1); acc8(a[i], r2); acc8(a[i], r3);
                        }
                        for (; j < cc; ++j) {
                            int s = __shfl(nb, lanebase + j);
                            uint4 r = *(const uint4*)&xin[(size_t)s * DIN + sub * 8];
                            acc8(a[i], r);
                        }
                    }
                }
            }
            __syncthreads();   // phase alignment within block
        }

        #pragma unroll
        for (int i = 0; i < NPG; ++i) {
            const int row = gloc * NPG + i;
            const float invd = 1.0f / fmaxf((float)dg[i], 1.0f);
            unsigned short u[8];
            #pragma unroll
            for (int q = 0; q < 8; ++q) u[q] = bf16bits(a[i][q] * invd);
            *(short8*)&A[row * KP + sub * 8] = *(short8*)u;
        }
    }
    __syncthreads();

    // ---- Phase B: MFMA ----
    constexpr int WR  = NT / 16;   // row-tiles (4 or 2)
    constexpr int NCG = 4 / WR;    // col-groups (1 or 2)
    constexpr int OT  = 8 / NCG;   // out-tiles per wave (8 or 4)
    const int lane = tid & 63;
    const int wv   = tid >> 6;
    const int wr   = wv % WR;      // row-tile of this wave
    const int wc   = wv / WR;      // col-group of this wave
    const int l15  = lane & 15;
    const int kseg = lane >> 4;

    f32x4 acc[OT];
    #pragma unroll
    for (int ot = 0; ot < OT; ++ot) acc[ot] = (f32x4){0.f, 0.f, 0.f, 0.f};

    #pragma unroll
    for (int kk = 0; kk < K / 32; ++kk) {
        short8 av = *(const short8*)&A[(wr * 16 + l15) * KP + kk * 32 + kseg * 8];
        #pragma unroll
        for (int ot = 0; ot < OT; ++ot) {
            const int o16 = wc * OT + ot;   // 16-wide output tile index
            short8 b = *(const short8*)&Wcat[(size_t)(o16 * 16 + l15) * K + kk * 32 + kseg * 8];
            acc[ot] = __builtin_amdgcn_mfma_f32_16x16x32_bf16(av, b, acc[ot], 0, 0, 0);
        }
    }

    // ---- Epilogue ----
    #pragma unroll
    for (int ot = 0; ot < OT; ++ot) {
        const int o  = (wc * OT + ot) * 16 + l15;
        const float bv = bias[o];
        #pragma unroll
        for (int i = 0; i < 4; ++i) {
            int n = nbase + wr * 16 + kseg * 4 + i;
            if (n < n_nodes) {
                float v = acc[ot][i] + bv;
                if constexpr (RELU) v = fmaxf(v, 0.0f);
                if constexpr (OUT_BF16) {
                    ((unsigned short*)out)[(size_t)n * 128 + o] = bf16bits(v);
                } else {
                    ((float*)out)[(size_t)n * 128 + o] = v;
                }
            }
        }
    }
}

// ---------------------------------------------------------------------------
extern "C" void kernel_launch(void* const* d_in, const int* in_sizes, int n_in,
                              void* d_out, int out_size, void* d_ws, size_t ws_size,
                              hipStream_t stream) {
    const float* x   = (const float*)d_in[0];
    const int*   ei  = (const int*)d_in[1];   // [2, E] int32
    const float* W1l = (const float*)d_in[2];
    const float* W1r = (const float*)d_in[3];
    const float* b1  = (const float*)d_in[4];
    const float* W2l = (const float*)d_in[5];
    const float* W2r = (const float*)d_in[6];
    const float* b2  = (const float*)d_in[7];
    float*       out = (float*)d_out;

    const int* src = ei;       // edge_index[0]
    const int* dst = ei + E;   // edge_index[1]

    // Workspace (16B-aligned bump allocator), ~27 MB total
    char* p = (char*)d_ws;
    auto alloc = [&](size_t bytes) -> char* {
        char* r = p; p += (bytes + 15) & ~(size_t)15; return r;
    };
    int*            cnt8  = (int*)alloc((size_t)N * 8 * sizeof(int));     // 1.6 MB
    unsigned short* bin   = (unsigned short*)alloc((size_t)N * BSTR * 2); // 12.8 MB
    unsigned short* xb    = (unsigned short*)alloc((size_t)N * D0 * 2);
    unsigned short* h     = (unsigned short*)alloc((size_t)N * D1 * 2);
    unsigned short* W1cat = (unsigned short*)alloc(128 * 128 * 2);
    unsigned short* W2cat = (unsigned short*)alloc(128 * 256 * 2);

    // ---- fused prep: zero cnt8, cvt x, pack weights ----
    k_prep<<<(N * D0 / 8 + 255) / 256, 256, 0, stream>>>(
        x, xb, W1l, W1r, W2l, W2r, W1cat, W2cat, cnt8);

    // ---- adjacency build: one XCD-partitioned atomic pass, sub-binned ----
    k_bin<<<NPART * BPP, 256, 0, stream>>>(src, dst, cnt8, bin);

    // ---- Layer 1 (fused, NT=64): xb -> h (ReLU, bf16) ----
    k_layer<D0, 64, /*RELU=*/true, /*OUT_BF16=*/true>
        <<<(N + 63) / 64, 256, 0, stream>>>(xb, cnt8, bin, W1cat, b1, h, N);

    // ---- Layer 2 (fused, NT=32): h -> out (f32) ----
    k_layer<D1, 32, /*RELU=*/false, /*OUT_BF16=*/false>
        <<<(N + 31) / 32, 256, 0, stream>>>(h, cnt8, bin, W2cat, b2, out, N);
}

// Round 18
// 166.556 us; speedup vs baseline: 1.1261x; 1.1261x over previous
//
#include <hip/hip_runtime.h>
#include <hip/hip_bf16.h>

// Problem constants (from reference)
constexpr int N  = 50000;   // nodes
constexpr int E  = 800000;  // edges
constexpr int D0 = 64;      // IN_DIM
constexpr int D1 = 128;     // HID_DIM

// Sub-binned-then-compacted adjacency: k_bin buckets neighbors by src range
// (src>>13, 7 ranges); k_compact squeezes them into a contiguous src-sorted
// list. Gather walks the contiguous list (full 4-deep MLP) while co-resident
// blocks progress in soft lockstep through the same src ranges -> L2-local.
constexpr int SB   = 7;     // src ranges: 50000/8192 -> sb in 0..6
constexpr int SC   = 16;    // per-sub-bin capacity (Poisson(2.62); P(>16)~3e-9)
constexpr int BSTR = 128;   // bin row stride in ushorts

constexpr int NPART = 8;                       // XCD count
constexpr int PSZ   = (N + NPART - 1) / NPART; // 6250 nodes per partition
constexpr int BPP   = 128;                     // blocks per partition

typedef __attribute__((ext_vector_type(8))) short short8;   // 8 bf16 = 4 VGPR
typedef __attribute__((ext_vector_type(4))) float f32x4;

__device__ __forceinline__ unsigned short bf16bits(float f) {
    __hip_bfloat16 hb = __float2bfloat16(f);
    return *reinterpret_cast<unsigned short*>(&hb);
}

// accumulate 8 bf16 (packed in uint4) into 8 f32 accumulators
__device__ __forceinline__ void acc8(float* a, const uint4 r) {
    union { unsigned u; float f; } c;
    c.u = r.x << 16;         a[0] += c.f;
    c.u = r.x & 0xffff0000u; a[1] += c.f;
    c.u = r.y << 16;         a[2] += c.f;
    c.u = r.y & 0xffff0000u; a[3] += c.f;
    c.u = r.z << 16;         a[4] += c.f;
    c.u = r.z & 0xffff0000u; a[5] += c.f;
    c.u = r.w << 16;         a[6] += c.f;
    c.u = r.w & 0xffff0000u; a[7] += c.f;
}

// ---------------------------------------------------------------------------
// Fused prep: zero cnt8, convert x -> bf16, pack weights -> bf16.
// ---------------------------------------------------------------------------
__global__ __launch_bounds__(256)
void k_prep(const float* __restrict__ x, unsigned short* __restrict__ xb,
            const float* __restrict__ W1l, const float* __restrict__ W1r,
            const float* __restrict__ W2l, const float* __restrict__ W2r,
            unsigned short* __restrict__ W1cat, unsigned short* __restrict__ W2cat,
            int* __restrict__ cnt8) {
    int i = blockIdx.x * blockDim.x + threadIdx.x;
    if (i < N * 8 / 4) ((int4*)cnt8)[i] = make_int4(0, 0, 0, 0);
    if (i < 128 * 128) {
        int o = i >> 7, k = i & 127;
        float v = (k < 64) ? W1l[o * 64 + k] : W1r[o * 64 + (k - 64)];
        W1cat[i] = bf16bits(v);
    }
    if (i < 128 * 256) {
        int o = i >> 8, k = i & 255;
        float v = (k < 128) ? W2l[o * 128 + k] : W2r[o * 128 + (k - 128)];
        W2cat[i] = bf16bits(v);
    }
    if (i < N * D0 / 8) {
        const float4 v0 = *(const float4*)&x[(size_t)i * 8];
        const float4 v1 = *(const float4*)&x[(size_t)i * 8 + 4];
        float f[8] = {v0.x, v0.y, v0.z, v0.w, v1.x, v1.y, v1.z, v1.w};
        unsigned short u[8];
        #pragma unroll
        for (int j = 0; j < 8; ++j) u[j] = bf16bits(f[j]);
        *(short8*)&xb[(size_t)i * 8] = *(short8*)u;
    }
}

// ---------------------------------------------------------------------------
// XCD-partitioned binning into src-range sub-bins (round-17's k_bin):
// blocks with blockIdx%8==p handle dst range [p*PSZ,(p+1)*PSZ) exclusively,
// so cnt8 atomics + bin stores stay in one XCD's L2. Mapping is a locality
// heuristic only (G16).
// ---------------------------------------------------------------------------
__global__ __launch_bounds__(256)
void k_bin(const int* __restrict__ src, const int* __restrict__ dst,
           int* __restrict__ cnt8, unsigned short* __restrict__ bin) {
    const int p     = blockIdx.x & (NPART - 1);
    const int local = blockIdx.x >> 3;
    const int lo = p * PSZ;
    const int hi = min(N, lo + PSZ);

    for (int i = local * 256 + threadIdx.x; i < E / 4; i += BPP * 256) {
        const int e0 = i * 4;
        int4 d = *(const int4*)&dst[e0];
        int4 s = *(const int4*)&src[e0];
        if (d.x >= lo && d.x < hi) {
            int sb = s.x >> 13;
            int pos = atomicAdd(&cnt8[d.x * 8 + sb], 1);
            if (pos < SC) bin[(size_t)d.x * BSTR + sb * SC + pos] = (unsigned short)s.x;
        }
        if (d.y >= lo && d.y < hi) {
            int sb = s.y >> 13;
            int pos = atomicAdd(&cnt8[d.y * 8 + sb], 1);
            if (pos < SC) bin[(size_t)d.y * BSTR + sb * SC + pos] = (unsigned short)s.y;
        }
        if (d.z >= lo && d.z < hi) {
            int sb = s.z >> 13;
            int pos = atomicAdd(&cnt8[d.z * 8 + sb], 1);
            if (pos < SC) bin[(size_t)d.z * BSTR + sb * SC + pos] = (unsigned short)s.z;
        }
        if (d.w >= lo && d.w < hi) {
            int sb = s.w >> 13;
            int pos = atomicAdd(&cnt8[d.w * 8 + sb], 1);
            if (pos < SC) bin[(size_t)d.w * BSTR + sb * SC + pos] = (unsigned short)s.w;
        }
    }
}

// ---------------------------------------------------------------------------
// Compact: squeeze each node's 7 sub-bin fragments into a contiguous
// src-range-sorted prefix of its bin row (in place; dest offset <= src
// offset always, so forward copies are safe). One thread per node.
// cntc[n] = raw_degree | (compact_len << 16).
// ---------------------------------------------------------------------------
__global__ __launch_bounds__(256)
void k_compact(const int* __restrict__ cnt8, unsigned short* __restrict__ bin,
               int* __restrict__ cntc) {
    int n = blockIdx.x * blockDim.x + threadIdx.x;
    if (n >= N) return;
    unsigned short* row = bin + (size_t)n * BSTR;
    int raw_total = 0;
    int cur = 0;
    #pragma unroll
    for (int sb = 0; sb < SB; ++sb) {
        int raw = cnt8[n * 8 + sb];
        raw_total += raw;
        int c = min(raw, SC);
        int srcoff = sb * SC;
        if (cur != srcoff) {
            for (int j = 0; j < c; ++j) row[cur + j] = row[srcoff + j];
        }
        cur += c;
    }
    cntc[n] = raw_total | (cur << 16);
}

// ---------------------------------------------------------------------------
// Fused SAGE layer: gather-mean (phase A, contiguous src-sorted walk,
// 4-deep MLP -- round-16's measured-best inner loop) + MFMA dense (phase B).
// Soft phase alignment: co-resident blocks walk src-sorted lists at similar
// rates -> device-wide reads concentrate in the same ~2MB src range.
// Phase B tiling/fragment layouts per m89/m91.
// ---------------------------------------------------------------------------
template<int DIN, int NT, bool RELU, bool OUT_BF16>
__global__ __launch_bounds__(256)
void k_layer(const unsigned short* __restrict__ xin,  // bf16 [N][DIN]
             const int* __restrict__ cntc,            // raw | (clen<<16)
             const unsigned short* __restrict__ bin,  // [N][BSTR] compacted
             const unsigned short* __restrict__ Wcat, // [128][2*DIN] bf16
             const float* __restrict__ bias,
             void* __restrict__ out,
             int n_nodes) {
    constexpr int K  = 2 * DIN;       // 128 or 256
    constexpr int KP = K + 8;         // padded row (bf16 units)
    __shared__ unsigned short A[NT * KP];

    const int tid   = threadIdx.x;
    const int nbase = blockIdx.x * NT;

    // ---- Phase A1: root copy into right half of A ----
    constexpr int CPR = DIN / 8;
    for (int c = tid; c < NT * CPR; c += 256) {
        int row  = c / CPR;
        int col8 = (c - row * CPR) * 8;
        int n    = nbase + row;
        short8 v = (short8)0;
        if (n < n_nodes) v = *(const short8*)&xin[(size_t)n * DIN + col8];
        *(short8*)&A[row * KP + DIN + col8] = v;
    }

    // ---- Phase A2: gather-mean into left half of A ----
    {
        constexpr int GRPSZ = DIN / 8;      // 8 (D0) or 16 (D1)
        constexpr int NGRP  = 256 / GRPSZ;  // 32 or 16 groups per block
        constexpr int NPG   = NT / NGRP;    // nodes per group
        const int sub      = tid & (GRPSZ - 1);
        const int gloc     = tid / GRPSZ;
        const int lane     = tid & 63;
        const int lanebase = (lane / GRPSZ) * GRPSZ;

        #pragma unroll
        for (int i = 0; i < NPG; ++i) {
            const int row = gloc * NPG + i;
            const int n   = nbase + row;

            float a[8] = {0.f, 0.f, 0.f, 0.f, 0.f, 0.f, 0.f, 0.f};
            int deg = 0;
            if (n < n_nodes) {
                const int cc = cntc[n];
                deg = cc & 0xffff;
                const int clen = cc >> 16;
                const size_t base = (size_t)n * BSTR;
                for (int b = 0; b < clen; b += GRPSZ) {
                    int nb = (b + sub < clen) ? (int)bin[base + b + sub] : 0;
                    const int c = min(GRPSZ, clen - b);
                    int j = 0;
                    for (; j + 4 <= c; j += 4) {
                        int s0 = __shfl(nb, lanebase + j + 0);
                        int s1 = __shfl(nb, lanebase + j + 1);
                        int s2 = __shfl(nb, lanebase + j + 2);
                        int s3 = __shfl(nb, lanebase + j + 3);
                        uint4 r0 = *(const uint4*)&xin[(size_t)s0 * DIN + sub * 8];
                        uint4 r1 = *(const uint4*)&xin[(size_t)s1 * DIN + sub * 8];
                        uint4 r2 = *(const uint4*)&xin[(size_t)s2 * DIN + sub * 8];
                        uint4 r3 = *(const uint4*)&xin[(size_t)s3 * DIN + sub * 8];
                        acc8(a, r0); acc8(a, r1); acc8(a, r2); acc8(a, r3);
                    }
                    for (; j < c; ++j) {
                        int s = __shfl(nb, lanebase + j);
                        uint4 r = *(const uint4*)&xin[(size_t)s * DIN + sub * 8];
                        acc8(a, r);
                    }
                }
            }

            const float invd = 1.0f / fmaxf((float)deg, 1.0f);
            unsigned short u[8];
            #pragma unroll
            for (int q = 0; q < 8; ++q) u[q] = bf16bits(a[q] * invd);
            *(short8*)&A[row * KP + sub * 8] = *(short8*)u;
        }
    }
    __syncthreads();

    // ---- Phase B: MFMA ----
    constexpr int WR  = NT / 16;   // row-tiles (4 or 2)
    constexpr int NCG = 4 / WR;    // col-groups (1 or 2)
    constexpr int OT  = 8 / NCG;   // out-tiles per wave (8 or 4)
    const int lane = tid & 63;
    const int wv   = tid >> 6;
    const int wr   = wv % WR;
    const int wc   = wv / WR;
    const int l15  = lane & 15;
    const int kseg = lane >> 4;

    f32x4 acc[OT];
    #pragma unroll
    for (int ot = 0; ot < OT; ++ot) acc[ot] = (f32x4){0.f, 0.f, 0.f, 0.f};

    #pragma unroll
    for (int kk = 0; kk < K / 32; ++kk) {
        short8 av = *(const short8*)&A[(wr * 16 + l15) * KP + kk * 32 + kseg * 8];
        #pragma unroll
        for (int ot = 0; ot < OT; ++ot) {
            const int o16 = wc * OT + ot;
            short8 b = *(const short8*)&Wcat[(size_t)(o16 * 16 + l15) * K + kk * 32 + kseg * 8];
            acc[ot] = __builtin_amdgcn_mfma_f32_16x16x32_bf16(av, b, acc[ot], 0, 0, 0);
        }
    }

    // ---- Epilogue ----
    #pragma unroll
    for (int ot = 0; ot < OT; ++ot) {
        const int o  = (wc * OT + ot) * 16 + l15;
        const float bv = bias[o];
        #pragma unroll
        for (int i = 0; i < 4; ++i) {
            int n = nbase + wr * 16 + kseg * 4 + i;
            if (n < n_nodes) {
                float v = acc[ot][i] + bv;
                if constexpr (RELU) v = fmaxf(v, 0.0f);
                if constexpr (OUT_BF16) {
                    ((unsigned short*)out)[(size_t)n * 128 + o] = bf16bits(v);
                } else {
                    ((float*)out)[(size_t)n * 128 + o] = v;
                }
            }
        }
    }
}

// ---------------------------------------------------------------------------
extern "C" void kernel_launch(void* const* d_in, const int* in_sizes, int n_in,
                              void* d_out, int out_size, void* d_ws, size_t ws_size,
                              hipStream_t stream) {
    const float* x   = (const float*)d_in[0];
    const int*   ei  = (const int*)d_in[1];   // [2, E] int32
    const float* W1l = (const float*)d_in[2];
    const float* W1r = (const float*)d_in[3];
    const float* b1  = (const float*)d_in[4];
    const float* W2l = (const float*)d_in[5];
    const float* W2r = (const float*)d_in[6];
    const float* b2  = (const float*)d_in[7];
    float*       out = (float*)d_out;

    const int* src = ei;       // edge_index[0]
    const int* dst = ei + E;   // edge_index[1]

    // Workspace (16B-aligned bump allocator), ~28 MB total
    char* p = (char*)d_ws;
    auto alloc = [&](size_t bytes) -> char* {
        char* r = p; p += (bytes + 15) & ~(size_t)15; return r;
    };
    int*            cnt8  = (int*)alloc((size_t)N * 8 * sizeof(int));     // 1.6 MB
    int*            cntc  = (int*)alloc((size_t)N * sizeof(int));         // 0.2 MB
    unsigned short* bin   = (unsigned short*)alloc((size_t)N * BSTR * 2); // 12.8 MB
    unsigned short* xb    = (unsigned short*)alloc((size_t)N * D0 * 2);
    unsigned short* h     = (unsigned short*)alloc((size_t)N * D1 * 2);
    unsigned short* W1cat = (unsigned short*)alloc(128 * 128 * 2);
    unsigned short* W2cat = (unsigned short*)alloc(128 * 256 * 2);

    // ---- fused prep: zero cnt8, cvt x, pack weights ----
    k_prep<<<(N * D0 / 8 + 255) / 256, 256, 0, stream>>>(
        x, xb, W1l, W1r, W2l, W2r, W1cat, W2cat, cnt8);

    // ---- adjacency build: sub-binned atomic pass + in-place compaction ----
    k_bin<<<NPART * BPP, 256, 0, stream>>>(src, dst, cnt8, bin);
    k_compact<<<(N + 255) / 256, 256, 0, stream>>>(cnt8, bin, cntc);

    // ---- Layer 1 (fused, NT=64): xb -> h (ReLU, bf16) ----
    k_layer<D0, 64, /*RELU=*/true, /*OUT_BF16=*/true>
        <<<(N + 63) / 64, 256, 0, stream>>>(xb, cntc, bin, W1cat, b1, h, N);

    // ---- Layer 2 (fused, NT=32): h -> out (f32) ----
    k_layer<D1, 32, /*RELU=*/false, /*OUT_BF16=*/false>
        <<<(N + 31) / 32, 256, 0, stream>>>(h, cntc, bin, W2cat, b2, out, N);
}